// Round 2
// baseline (472.772 us; speedup 1.0000x reference)
//
#include <hip/hip_runtime.h>

// ---------------------------------------------------------------------------
// RelativeStructureAttention (Music-Transformer style) on MI355X / gfx950.
//   b=2, n=1024, dim=1024, HEADS=16, d_h=64. Inputs fp32 (+int32 idx), out fp32.
// Pipeline:
//   0) cast_f32_bf16  x, Wq, Wk, Wv, Wo, Er -> bf16 copies in ws
//   1) gemm_bt   x@Wq^T, x@Wk^T, x@Wv^T  -> ws Qb/Kb/Vb  (bf16, (b,n,h*d))
//   2) qe_kernel per (b,h,i): 151 dots q . table_row / 8 -> ws QE (fp32)
//   3) attn      flash attention per (b,h,64-row i-tile):
//                scores = q/8 . k  +  q/8 . Er[1023-i+j]  + gathered QE biases
//   4) gemm_bt<f32out>   O@Wo^T -> d_out (fp32)
// ---------------------------------------------------------------------------

using bf16x8 = __attribute__((ext_vector_type(8))) short;
using f32x4  = __attribute__((ext_vector_type(4))) float;

__device__ __forceinline__ float bf2f(unsigned short u) {
  unsigned x = ((unsigned)u) << 16;
  float f;
  __builtin_memcpy(&f, &x, 4);
  return f;
}
__device__ __forceinline__ unsigned short f2bf(float f) {
  unsigned x;
  __builtin_memcpy(&x, &f, 4);
  unsigned r = (x + 0x7FFFu + ((x >> 16) & 1u)) >> 16;  // round-nearest-even
  return (unsigned short)r;
}

union B8 { bf16x8 v; unsigned short u[8]; };

// ---------------------------------------------------------------------------
// fp32 -> bf16 elementwise cast (n % 4 == 0 for all our buffers)
// ---------------------------------------------------------------------------
__global__ __launch_bounds__(256) void cast_f32_bf16(const float* __restrict__ src,
                                                     unsigned short* __restrict__ dst,
                                                     int n)
{
  const int m = n >> 2;
  for (int i = blockIdx.x * blockDim.x + threadIdx.x; i < m; i += gridDim.x * blockDim.x) {
    const float4 v = ((const float4*)src)[i];
    ushort4 o;
    o.x = f2bf(v.x); o.y = f2bf(v.y); o.z = f2bf(v.z); o.w = f2bf(v.w);
    ((ushort4*)dst)[i] = o;
  }
}

// ---------------------------------------------------------------------------
// C[m][n] = sum_k A[m][k] * B[n][k]   (A: MxK bf16, B: NxK bf16)
// block 256 = 4 waves; block tile 64x64; wave w: rows w*16..+16, cols 0..63.
// MFMA 16x16x32 bf16. A-frag: A[m=lane&15][k=quad*8+e]; D: row=quad*4+reg,
// col=lane&15 (guide §3, HW-verified m89/m91).
// ---------------------------------------------------------------------------
template <bool F32OUT>
__global__ __launch_bounds__(256) void gemm_bt(const unsigned short* __restrict__ A,
                                               const unsigned short* __restrict__ B,
                                               void* __restrict__ Cv,
                                               int M, int N, int K)
{
  const int n0 = blockIdx.x * 64;
  const int m0 = blockIdx.y * 64;
  const int tid = threadIdx.x;
  const int w = tid >> 6, lane = tid & 63;
  const int c15 = lane & 15, q = lane >> 4;

  const unsigned short* arow = A + (size_t)(m0 + w * 16 + c15) * K + q * 8;
  const unsigned short* brow = B + (size_t)(n0 + c15) * K + q * 8;

  f32x4 acc[4];
  #pragma unroll
  for (int nt = 0; nt < 4; nt++) { acc[nt][0]=0.f; acc[nt][1]=0.f; acc[nt][2]=0.f; acc[nt][3]=0.f; }

  for (int k = 0; k < K; k += 32) {
    bf16x8 a = *(const bf16x8*)(arow + k);
    #pragma unroll
    for (int nt = 0; nt < 4; nt++) {
      bf16x8 b = *(const bf16x8*)(brow + (size_t)nt * 16 * K + k);
      acc[nt] = __builtin_amdgcn_mfma_f32_16x16x32_bf16(a, b, acc[nt], 0, 0, 0);
    }
  }
  #pragma unroll
  for (int nt = 0; nt < 4; nt++)
    #pragma unroll
    for (int r = 0; r < 4; r++) {
      const int m = m0 + w * 16 + q * 4 + r;
      const int n = n0 + nt * 16 + c15;
      if constexpr (F32OUT) ((float*)Cv)[(size_t)m * N + n] = acc[nt][r];
      else ((unsigned short*)Cv)[(size_t)m * N + n] = f2bf(acc[nt][r]);
    }
}

// ---------------------------------------------------------------------------
// QE[b,h,i,s] = 0.125 * dot(q[b,h,i,:], table_row(s))  (fp32, stride 152)
// s layout: [0..16]=bar(16 rows + zero), [17..112]=pos(95+zero),
//           [113..137]=oct(24+zero), [138..150]=sem(12+zero). zero rows -> 0.
// grid = b*n blocks; block 256. Tables read as fp32 directly.
// ---------------------------------------------------------------------------
__global__ __launch_bounds__(256) void qe_kernel(
    const unsigned short* __restrict__ Qb,
    const float* __restrict__ Tb, const float* __restrict__ Tp,
    const float* __restrict__ To, const float* __restrict__ Ts,
    float* __restrict__ QE)
{
  __shared__ float qrow[1024];
  __shared__ float tbl[147][65];  // +1 pad: avoids 64-stride bank conflicts
  const int bb = blockIdx.x >> 10;
  const int i  = blockIdx.x & 1023;
  const int tid = threadIdx.x;

  const unsigned short* qp = Qb + ((size_t)bb * 1024 + i) * 1024;
  for (int t = tid; t < 1024; t += 256) qrow[t] = bf2f(qp[t]);
  for (int t = tid; t < 147 * 64; t += 256) {
    const int r = t >> 6, d = t & 63;
    float v;
    if (r < 16)       v = Tb[r * 64 + d];
    else if (r < 111) v = Tp[(r - 16) * 64 + d];
    else if (r < 135) v = To[(r - 111) * 64 + d];
    else              v = Ts[(r - 135) * 64 + d];
    tbl[r][d] = v;
  }
  __syncthreads();

  if (tid < 151) {
    const int s = tid;
    int row;
    if (s < 17)       row = (s < 16)  ? s               : -1;
    else if (s < 113) row = (s < 112) ? 16 + (s - 17)   : -1;
    else if (s < 138) row = (s < 137) ? 111 + (s - 113) : -1;
    else              row = (s < 150) ? 135 + (s - 138) : -1;
    for (int h = 0; h < 16; h++) {
      float acc = 0.f;
      if (row >= 0) {
        #pragma unroll 8
        for (int d = 0; d < 64; d++) acc += qrow[h * 64 + d] * tbl[row][d];
      }
      QE[(((size_t)bb * 16 + h) * 1024 + i) * 152 + s] = 0.125f * acc;
    }
  }
}

// ---------------------------------------------------------------------------
// Flash attention with relative/structure biases.
// grid (h=16, it=16, b=2); block 256 = 4 waves; wave w owns i-rows iw..iw+15.
// LDS 56 KB total -> 2 blocks/CU.
// Srel[i,j] = q_i . Er[1023-i+j] (j<=i): C2[m][p] = q_m . Er[rbase+p],
//   rbase = 960-i0+j0; wave w computes MFMA tiles pt=3-w..7-w, stores at
//   local col L; read back at L = 15-m+jj (w-independent).
// ---------------------------------------------------------------------------
__global__ __launch_bounds__(256) void attn_kernel(
    const unsigned short* __restrict__ Qb,
    const unsigned short* __restrict__ Kb,
    const unsigned short* __restrict__ Vb,
    const float* __restrict__ QE,
    const int* __restrict__ rbar, const int* __restrict__ rpos,
    const int* __restrict__ roct, const int* __restrict__ rsem,
    const unsigned short* __restrict__ Er,
    unsigned short* __restrict__ Ob)
{
  const int h  = blockIdx.x;
  const int it = blockIdx.y;
  const int bb = blockIdx.z;
  const int i0 = it * 64;
  const int tid = threadIdx.x;
  const int w = tid >> 6;
  const int lane = tid & 63;
  const int c15 = lane & 15;
  const int q = lane >> 4;

  // +8 row pad on bf16 tiles: 144 B stride -> 2-way LDS conflicts (free, m136)
  __shared__ __align__(16) unsigned short Klds[64][72];
  __shared__ __align__(16) unsigned short Vtlds[64][72];   // V transposed: [d][j]
  __shared__ __align__(16) unsigned short Elds[128][72];   // Er band
  __shared__ __align__(16) float C2[4][16 * 80];           // per-wave scratch (Srel, then P)
  float* c2w = &C2[w][0];

  // Q fragments, pre-scaled by 1/sqrt(d) = 1/8 (all score terms linear in q)
  bf16x8 qf[2];
  {
    const unsigned short* qp = Qb + ((size_t)bb * 1024 + i0 + w * 16 + c15) * 1024 + h * 64;
    #pragma unroll
    for (int kk = 0; kk < 2; kk++) {
      B8 t;
      t.v = *(const bf16x8*)(qp + kk * 32 + q * 8);
      #pragma unroll
      for (int e = 0; e < 8; e++) t.u[e] = f2bf(bf2f(t.u[e]) * 0.125f);
      qf[kk] = t.v;
    }
  }

  f32x4 Oa[4];
  float mrow[4], lrow[4];
  #pragma unroll
  for (int dt = 0; dt < 4; dt++) { Oa[dt][0]=0.f; Oa[dt][1]=0.f; Oa[dt][2]=0.f; Oa[dt][3]=0.f; }
  #pragma unroll
  for (int r = 0; r < 4; r++) { mrow[r] = -3e38f; lrow[r] = 0.f; }

  const unsigned short* kbase = Kb + (size_t)bb * 1024 * 1024 + h * 64;
  const unsigned short* vbase = Vb + (size_t)bb * 1024 * 1024 + h * 64;
  const int rowq = q * 4;                  // + r = D-row within wave tile
  const int iw = i0 + w * 16;              // wave's first absolute i-row
  const float* qe0 = QE + (((size_t)bb * 16 + h) * 1024 + iw + rowq) * 152;
  const size_t idx0 = ((size_t)bb * 1024 + iw + rowq) * 1024;

  for (int jt = 0; jt <= it; jt++) {
    const int j0 = jt * 64;
    __syncthreads();  // previous iteration's LDS consumers done

    // ---- stage K (row-major), V^T, Er band ----
    {
      const int row = tid >> 2, cs = (tid & 3) * 16;
      const unsigned short* ks = kbase + (size_t)(j0 + row) * 1024 + cs;
      *(bf16x8*)&Klds[row][cs]     = *(const bf16x8*)ks;
      *(bf16x8*)&Klds[row][cs + 8] = *(const bf16x8*)(ks + 8);
      const unsigned short* vs = vbase + (size_t)(j0 + row) * 1024 + cs;
      B8 v0, v1;
      v0.v = *(const bf16x8*)vs;
      v1.v = *(const bf16x8*)(vs + 8);
      #pragma unroll
      for (int e = 0; e < 8; e++) {
        Vtlds[cs + e][row]     = v0.u[e];
        Vtlds[cs + 8 + e][row] = v1.u[e];
      }
      const int er = tid >> 1, ecs = (tid & 1) * 32;
      int rsrc = 960 - i0 + j0 + er;       // >= 0 always; clamp masked overrun
      if (rsrc > 1023) rsrc = 1023;
      const unsigned short* es = Er + (size_t)rsrc * 64 + ecs;
      *(bf16x8*)&Elds[er][ecs]      = *(const bf16x8*)es;
      *(bf16x8*)&Elds[er][ecs + 8]  = *(const bf16x8*)(es + 8);
      *(bf16x8*)&Elds[er][ecs + 16] = *(const bf16x8*)(es + 16);
      *(bf16x8*)&Elds[er][ecs + 24] = *(const bf16x8*)(es + 24);
    }
    __syncthreads();

    // ---- QK^T ----
    f32x4 S[4];
    #pragma unroll
    for (int nt = 0; nt < 4; nt++) {
      f32x4 a; a[0]=0.f; a[1]=0.f; a[2]=0.f; a[3]=0.f;
      bf16x8 k0 = *(const bf16x8*)&Klds[nt * 16 + c15][q * 8];
      bf16x8 k1 = *(const bf16x8*)&Klds[nt * 16 + c15][32 + q * 8];
      a = __builtin_amdgcn_mfma_f32_16x16x32_bf16(qf[0], k0, a, 0, 0, 0);
      a = __builtin_amdgcn_mfma_f32_16x16x32_bf16(qf[1], k1, a, 0, 0, 0);
      S[nt] = a;
    }

    // ---- C2 = q . Er-band (wave-windowed: 5 of 8 tiles) ----
    #pragma unroll
    for (int t5 = 0; t5 < 5; t5++) {
      const int pt = 3 - w + t5;
      f32x4 a; a[0]=0.f; a[1]=0.f; a[2]=0.f; a[3]=0.f;
      bf16x8 e0 = *(const bf16x8*)&Elds[pt * 16 + c15][q * 8];
      bf16x8 e1 = *(const bf16x8*)&Elds[pt * 16 + c15][32 + q * 8];
      a = __builtin_amdgcn_mfma_f32_16x16x32_bf16(qf[0], e0, a, 0, 0, 0);
      a = __builtin_amdgcn_mfma_f32_16x16x32_bf16(qf[1], e1, a, 0, 0, 0);
      #pragma unroll
      for (int r = 0; r < 4; r++)
        c2w[(rowq + r) * 80 + t5 * 16 + c15] = a[r];
    }

    // ---- assemble scores: + Srel + structure bias, causal mask ----
    #pragma unroll
    for (int nt = 0; nt < 4; nt++) {
      const int j = j0 + nt * 16 + c15;
      int ii[4][4];
      #pragma unroll
      for (int r = 0; r < 4; r++) {
        const size_t off = idx0 + (size_t)r * 1024 + j;
        ii[r][0] = rbar[off]; ii[r][1] = rpos[off];
        ii[r][2] = roct[off]; ii[r][3] = rsem[off];
      }
      #pragma unroll
      for (int r = 0; r < 4; r++) {
        const float* qe = qe0 + (size_t)r * 152;
        const float bias = qe[ii[r][0]] + qe[17 + ii[r][1]] + qe[113 + ii[r][2]] + qe[138 + ii[r][3]];
        const float srel = c2w[(rowq + r) * 80 + (15 - (rowq + r) + nt * 16 + c15)];
        float sc = S[nt][r] + srel + bias;
        if (jt == it && j > iw + rowq + r) sc = -3e38f;  // causal
        S[nt][r] = sc;
      }
    }

    // ---- online softmax (row stats live at (quad,reg), replicated x16 lanes) ----
    float alpha[4];
    #pragma unroll
    for (int r = 0; r < 4; r++) {
      float v = fmaxf(fmaxf(S[0][r], S[1][r]), fmaxf(S[2][r], S[3][r]));
      v = fmaxf(v, __shfl_xor(v, 1));
      v = fmaxf(v, __shfl_xor(v, 2));
      v = fmaxf(v, __shfl_xor(v, 4));
      v = fmaxf(v, __shfl_xor(v, 8));
      const float mn = fmaxf(mrow[r], v);
      alpha[r] = __expf(mrow[r] - mn);
      mrow[r] = mn;
    }
    #pragma unroll
    for (int nt = 0; nt < 4; nt++)
      #pragma unroll
      for (int r = 0; r < 4; r++)
        S[nt][r] = __expf(S[nt][r] - mrow[r]);
    #pragma unroll
    for (int r = 0; r < 4; r++) {
      float s = S[0][r] + S[1][r] + S[2][r] + S[3][r];
      s += __shfl_xor(s, 1);
      s += __shfl_xor(s, 2);
      s += __shfl_xor(s, 4);
      s += __shfl_xor(s, 8);
      lrow[r] = lrow[r] * alpha[r] + s;
      #pragma unroll
      for (int dt = 0; dt < 4; dt++) Oa[dt][r] *= alpha[r];
    }

    // ---- P round-trip through per-wave LDS (fp32) ----
    #pragma unroll
    for (int nt = 0; nt < 4; nt++)
      #pragma unroll
      for (int r = 0; r < 4; r++)
        c2w[(rowq + r) * 80 + nt * 16 + c15] = S[nt][r];

    bf16x8 pf[2];
    #pragma unroll
    for (int kk = 0; kk < 2; kk++) {
      const float* pr = &c2w[c15 * 80 + kk * 32 + q * 8];
      B8 t;
      #pragma unroll
      for (int e = 0; e < 8; e++) t.u[e] = f2bf(pr[e]);  // scalar reads: safe dep
      pf[kk] = t.v;
    }

    // ---- O += P @ V ----
    #pragma unroll
    for (int dt = 0; dt < 4; dt++) {
      bf16x8 v0 = *(const bf16x8*)&Vtlds[dt * 16 + c15][q * 8];
      bf16x8 v1 = *(const bf16x8*)&Vtlds[dt * 16 + c15][32 + q * 8];
      Oa[dt] = __builtin_amdgcn_mfma_f32_16x16x32_bf16(pf[0], v0, Oa[dt], 0, 0, 0);
      Oa[dt] = __builtin_amdgcn_mfma_f32_16x16x32_bf16(pf[1], v1, Oa[dt], 0, 0, 0);
    }
  }

  // ---- epilogue: O / l -> Ob (b, i, h*64+d) bf16 ----
  #pragma unroll
  for (int dt = 0; dt < 4; dt++)
    #pragma unroll
    for (int r = 0; r < 4; r++) {
      const int i_ = iw + rowq + r;
      const float o = Oa[dt][r] / lrow[r];
      Ob[((size_t)bb * 1024 + i_) * 1024 + h * 64 + dt * 16 + c15] = f2bf(o);
    }
}

// ---------------------------------------------------------------------------
extern "C" void kernel_launch(void* const* d_in, const int* in_sizes, int n_in,
                              void* d_out, int out_size, void* d_ws, size_t ws_size,
                              hipStream_t stream)
{
  const float* x    = (const float*)d_in[0];
  const int*   rbar = (const int*)d_in[1];
  const int*   rpos = (const int*)d_in[2];
  const int*   roct = (const int*)d_in[3];
  const int*   rsem = (const int*)d_in[4];
  const float* Wq   = (const float*)d_in[5];
  const float* Wk   = (const float*)d_in[6];
  const float* Wv   = (const float*)d_in[7];
  const float* Wo   = (const float*)d_in[8];
  const float* Er   = (const float*)d_in[9];
  const float* Tb   = (const float*)d_in[10];
  const float* Tp   = (const float*)d_in[11];
  const float* To   = (const float*)d_in[12];
  const float* Ts   = (const float*)d_in[13];
  float* out = (float*)d_out;

  // workspace layout (~49 MB)
  char* ws = (char*)d_ws;
  const size_t MB = 1u << 20;
  unsigned short* x_bf  = (unsigned short*)(ws);            //  0..4 MB
  unsigned short* Wq_bf = (unsigned short*)(ws + 4 * MB);   //  2 MB
  unsigned short* Wk_bf = (unsigned short*)(ws + 6 * MB);
  unsigned short* Wv_bf = (unsigned short*)(ws + 8 * MB);
  unsigned short* Wo_bf = (unsigned short*)(ws + 10 * MB);
  unsigned short* Er_bf = (unsigned short*)(ws + 12 * MB);  //  128 KB
  unsigned short* Qb    = (unsigned short*)(ws + 13 * MB);  //  4 MB
  unsigned short* Kb    = (unsigned short*)(ws + 17 * MB);
  unsigned short* Vb    = (unsigned short*)(ws + 21 * MB);
  unsigned short* Ob    = (unsigned short*)(ws + 25 * MB);
  float*          QE    = (float*)(ws + 29 * MB);           // 19.9 MB

  cast_f32_bf16<<<1024, 256, 0, stream>>>(x,  x_bf,  2 * 1024 * 1024);
  cast_f32_bf16<<<1024, 256, 0, stream>>>(Wq, Wq_bf, 1024 * 1024);
  cast_f32_bf16<<<1024, 256, 0, stream>>>(Wk, Wk_bf, 1024 * 1024);
  cast_f32_bf16<<<1024, 256, 0, stream>>>(Wv, Wv_bf, 1024 * 1024);
  cast_f32_bf16<<<1024, 256, 0, stream>>>(Wo, Wo_bf, 1024 * 1024);
  cast_f32_bf16<<<64,   256, 0, stream>>>(Er, Er_bf, 1024 * 64);

  const dim3 gb(16, 32);  // N/64, M/64 for 2048x1024x1024
  gemm_bt<false><<<gb, 256, 0, stream>>>(x_bf, Wq_bf, Qb, 2048, 1024, 1024);
  gemm_bt<false><<<gb, 256, 0, stream>>>(x_bf, Wk_bf, Kb, 2048, 1024, 1024);
  gemm_bt<false><<<gb, 256, 0, stream>>>(x_bf, Wv_bf, Vb, 2048, 1024, 1024);
  qe_kernel<<<2048, 256, 0, stream>>>(Qb, Tb, Tp, To, Ts, QE);
  attn_kernel<<<dim3(16, 16, 2), 256, 0, stream>>>(Qb, Kb, Vb, QE,
                                                   rbar, rpos, roct, rsem, Er_bf, Ob);
  gemm_bt<true><<<gb, 256, 0, stream>>>(Ob, Wo_bf, out, 2048, 1024, 1024);
}

// Round 3
// 418.252 us; speedup vs baseline: 1.1304x; 1.1304x over previous
//
#include <hip/hip_runtime.h>

// ---------------------------------------------------------------------------
// RelativeStructureAttention (Music-Transformer style) on MI355X / gfx950.
//   b=2, n=1024, dim=1024, HEADS=16, d_h=64. Inputs fp32 (+int32 idx), out fp32.
// Pipeline:
//   0) cast_f32_bf16  x, [Wq|Wk|Wv] (fused 3072x1024), Wo, Er -> bf16 in ws
//   1) gemm128   x@Wqkv^T -> QKVb (bf16, row stride 3072: Q|K|V)
//   2) qe_kernel per (b,i): 151x16 dots q . table_row / 8 -> ws QE (fp32)
//   3) attn      flash attention per (b,h,64-row i-tile)
//   4) gemm128<f32out>  O@Wo^T -> d_out (fp32)
// ---------------------------------------------------------------------------

using bf16x8 = __attribute__((ext_vector_type(8))) short;
using f32x4  = __attribute__((ext_vector_type(4))) float;

__device__ __forceinline__ float bf2f(unsigned short u) {
  unsigned x = ((unsigned)u) << 16;
  float f;
  __builtin_memcpy(&f, &x, 4);
  return f;
}
__device__ __forceinline__ unsigned short f2bf(float f) {
  unsigned x;
  __builtin_memcpy(&x, &f, 4);
  unsigned r = (x + 0x7FFFu + ((x >> 16) & 1u)) >> 16;  // round-nearest-even
  return (unsigned short)r;
}

union B8 { bf16x8 v; unsigned short u[8]; };

// async global->LDS, 16 B per lane (global_load_lds_dwordx4)
__device__ __forceinline__ void ld_lds16(const unsigned short* g, unsigned short* l) {
  __builtin_amdgcn_global_load_lds(
      (const __attribute__((address_space(1))) unsigned int*)g,
      (__attribute__((address_space(3))) unsigned int*)l, 16, 0, 0);
}

// ---------------------------------------------------------------------------
// fp32 -> bf16 elementwise cast (n % 4 == 0 for all our buffers)
// ---------------------------------------------------------------------------
__global__ __launch_bounds__(256) void cast_f32_bf16(const float* __restrict__ src,
                                                     unsigned short* __restrict__ dst,
                                                     int n)
{
  const int m = n >> 2;
  for (int i = blockIdx.x * blockDim.x + threadIdx.x; i < m; i += gridDim.x * blockDim.x) {
    const float4 v = ((const float4*)src)[i];
    ushort4 o;
    o.x = f2bf(v.x); o.y = f2bf(v.y); o.z = f2bf(v.z); o.w = f2bf(v.w);
    ((ushort4*)dst)[i] = o;
  }
}

// ---------------------------------------------------------------------------
// m97-style GEMM: C[m][n] = sum_k A[m][k]*B[n][k]; 128x128 block tile, BK=32,
// global_load_lds width 16, 2-barrier K-loop. 4 waves in 2x2; each wave 64x64
// (4x4 MFMA 16x16x32 tiles). LDS A/B tiles 128x32 bf16, unpadded, laid out in
// staging lane order (tid*16B) == row-major (row=tid/4, col=(tid%4)*8).
// ---------------------------------------------------------------------------
template <bool F32OUT>
__global__ __launch_bounds__(256) void gemm128(const unsigned short* __restrict__ A,
                                               const unsigned short* __restrict__ B,
                                               void* __restrict__ Cv,
                                               int M, int N, int K)
{
  __shared__ __align__(16) unsigned short Atile[128 * 32];
  __shared__ __align__(16) unsigned short Btile[128 * 32];
  const int tid = threadIdx.x;
  const int w = tid >> 6, lane = tid & 63;
  const int c15 = lane & 15, q = lane >> 4;
  const int wr = w >> 1, wc = w & 1;
  const int n0 = blockIdx.x * 128, m0 = blockIdx.y * 128;

  const unsigned short* ag = A + (size_t)(m0 + (tid >> 2)) * K + (tid & 3) * 8;
  const unsigned short* bg = B + (size_t)(n0 + (tid >> 2)) * K + (tid & 3) * 8;
  unsigned short* al = &Atile[tid * 8];
  unsigned short* bl = &Btile[tid * 8];
  const size_t half = (size_t)64 * K;

  f32x4 acc[4][4];
  #pragma unroll
  for (int mt = 0; mt < 4; mt++)
    #pragma unroll
    for (int nt = 0; nt < 4; nt++) { acc[mt][nt][0]=0.f; acc[mt][nt][1]=0.f; acc[mt][nt][2]=0.f; acc[mt][nt][3]=0.f; }

  for (int k0 = 0; k0 < K; k0 += 32) {
    __syncthreads();                       // prev iter's ds_reads done
    ld_lds16(ag + k0, al);                 // A rows 0..63
    ld_lds16(ag + half + k0, al + 2048);   // A rows 64..127
    ld_lds16(bg + k0, bl);
    ld_lds16(bg + half + k0, bl + 2048);
    __syncthreads();                       // drains vmcnt -> LDS filled

    bf16x8 af[4], bfr[4];
    #pragma unroll
    for (int mt = 0; mt < 4; mt++)
      af[mt] = *(const bf16x8*)&Atile[(wr * 64 + mt * 16 + c15) * 32 + q * 8];
    #pragma unroll
    for (int nt = 0; nt < 4; nt++)
      bfr[nt] = *(const bf16x8*)&Btile[(wc * 64 + nt * 16 + c15) * 32 + q * 8];
    #pragma unroll
    for (int mt = 0; mt < 4; mt++)
      #pragma unroll
      for (int nt = 0; nt < 4; nt++)
        acc[mt][nt] = __builtin_amdgcn_mfma_f32_16x16x32_bf16(af[mt], bfr[nt], acc[mt][nt], 0, 0, 0);
  }

  #pragma unroll
  for (int mt = 0; mt < 4; mt++)
    #pragma unroll
    for (int nt = 0; nt < 4; nt++)
      #pragma unroll
      for (int r = 0; r < 4; r++) {
        const int m = m0 + wr * 64 + mt * 16 + q * 4 + r;
        const int n = n0 + wc * 64 + nt * 16 + c15;
        if constexpr (F32OUT) ((float*)Cv)[(size_t)m * N + n] = acc[mt][nt][r];
        else ((unsigned short*)Cv)[(size_t)m * N + n] = f2bf(acc[mt][nt][r]);
      }
}

// ---------------------------------------------------------------------------
// QE[b,h,i,s] = 0.125 * dot(q[b,h,i,:], table_row(s))  (fp32, stride 152)
// s layout: [0..16]=bar(16+zero), [17..112]=pos(95+zero),
//           [113..137]=oct(24+zero), [138..150]=sem(12+zero).
// grid = b*n blocks; block 256; task space = 151 s x 16 h.
// Q rows come from fused QKV buffer (row stride 3072, Q at col 0).
// ---------------------------------------------------------------------------
__global__ __launch_bounds__(256) void qe_kernel(
    const unsigned short* __restrict__ QKV,
    const float* __restrict__ Tb, const float* __restrict__ Tp,
    const float* __restrict__ To, const float* __restrict__ Ts,
    float* __restrict__ QE)
{
  __shared__ float qrow[1024];
  __shared__ float tbl[147][65];  // +1 pad: avoids 64-stride bank conflicts
  const int bb = blockIdx.x >> 10;
  const int i  = blockIdx.x & 1023;
  const int tid = threadIdx.x;

  const unsigned short* qp = QKV + ((size_t)bb * 1024 + i) * 3072;
  for (int t = tid; t < 1024; t += 256) qrow[t] = bf2f(qp[t]);
  for (int t = tid; t < 147 * 64; t += 256) {
    const int r = t >> 6, d = t & 63;
    float v;
    if (r < 16)       v = Tb[r * 64 + d];
    else if (r < 111) v = Tp[(r - 16) * 64 + d];
    else if (r < 135) v = To[(r - 111) * 64 + d];
    else              v = Ts[(r - 135) * 64 + d];
    tbl[r][d] = v;
  }
  __syncthreads();

  for (int t = tid; t < 151 * 16; t += 256) {
    const int h = t / 151;
    const int s = t - h * 151;
    int row;
    if (s < 17)       row = (s < 16)  ? s               : -1;
    else if (s < 113) row = (s < 112) ? 16 + (s - 17)   : -1;
    else if (s < 138) row = (s < 137) ? 111 + (s - 113) : -1;
    else              row = (s < 150) ? 135 + (s - 138) : -1;
    float acc = 0.f;
    if (row >= 0) {
      #pragma unroll 8
      for (int d = 0; d < 64; d++) acc += qrow[h * 64 + d] * tbl[row][d];
    }
    QE[(((size_t)bb * 16 + h) * 1024 + i) * 152 + s] = 0.125f * acc;
  }
}

// ---------------------------------------------------------------------------
// Flash attention with relative/structure biases.
// grid (h=16, it=16, b=2); block 256 = 4 waves; wave w owns i-rows iw..iw+15.
// LDS 48128 B -> 3 blocks/CU (was 57344 -> 2).
// Srel[i,j] = q_i . Er[1023-i+j]: C2[m][p] = q_m . Er[rbase+p],
//   rbase = 960-i0+j0; wave w computes MFMA tiles pt=3-w..7-w, stores at
//   local col L = 15-m+jj (w-independent).  C2 kept in bf16 (stride 88:
//   16B-aligned rows, 2-way LDS conflicts only); P round-trip reads back
//   with a single ds_read_b128 per fragment half.
// ---------------------------------------------------------------------------
__global__ __launch_bounds__(256, 3) void attn_kernel(
    const unsigned short* __restrict__ QKV,
    const float* __restrict__ QE,
    const int* __restrict__ rbar, const int* __restrict__ rpos,
    const int* __restrict__ roct, const int* __restrict__ rsem,
    const unsigned short* __restrict__ Er,
    unsigned short* __restrict__ Ob)
{
  const int h  = blockIdx.x;
  const int it = blockIdx.y;
  const int bb = blockIdx.z;
  const int i0 = it * 64;
  const int tid = threadIdx.x;
  const int w = tid >> 6;
  const int lane = tid & 63;
  const int c15 = lane & 15;
  const int q = lane >> 4;

  // +8 row pad on bf16 tiles: 144 B stride -> 2-way LDS conflicts (free, m136)
  __shared__ __align__(16) unsigned short Klds[64][72];
  __shared__ __align__(16) unsigned short Vtlds[64][72];   // V transposed: [d][j]
  __shared__ __align__(16) unsigned short Elds[128][72];   // Er band
  __shared__ __align__(16) unsigned short C2[4][16 * 88];  // per-wave scratch (bf16)
  unsigned short* c2w = &C2[w][0];

  // Q fragments, pre-scaled by 1/sqrt(d) = 1/8 (all score terms linear in q)
  bf16x8 qf[2];
  {
    const unsigned short* qp = QKV + ((size_t)bb * 1024 + i0 + w * 16 + c15) * 3072 + h * 64;
    #pragma unroll
    for (int kk = 0; kk < 2; kk++) {
      B8 t;
      t.v = *(const bf16x8*)(qp + kk * 32 + q * 8);
      #pragma unroll
      for (int e = 0; e < 8; e++) t.u[e] = f2bf(bf2f(t.u[e]) * 0.125f);
      qf[kk] = t.v;
    }
  }

  f32x4 Oa[4];
  float mrow[4], lrow[4];
  #pragma unroll
  for (int dt = 0; dt < 4; dt++) { Oa[dt][0]=0.f; Oa[dt][1]=0.f; Oa[dt][2]=0.f; Oa[dt][3]=0.f; }
  #pragma unroll
  for (int r = 0; r < 4; r++) { mrow[r] = -3e38f; lrow[r] = 0.f; }

  const unsigned short* kbase = QKV + (size_t)bb * 1024 * 3072 + 1024 + h * 64;
  const unsigned short* vbase = QKV + (size_t)bb * 1024 * 3072 + 2048 + h * 64;
  const int rowq = q * 4;                  // + r = D-row within wave tile
  const int iw = i0 + w * 16;              // wave's first absolute i-row
  const float* qe0 = QE + (((size_t)bb * 16 + h) * 1024 + iw + rowq) * 152;
  const size_t idx0 = ((size_t)bb * 1024 + iw + rowq) * 1024;

  for (int jt = 0; jt <= it; jt++) {
    const int j0 = jt * 64;
    __syncthreads();  // previous iteration's LDS consumers done

    // ---- stage K (row-major), V^T, Er band ----
    {
      const int row = tid >> 2, cs = (tid & 3) * 16;
      const unsigned short* ks = kbase + (size_t)(j0 + row) * 3072 + cs;
      *(bf16x8*)&Klds[row][cs]     = *(const bf16x8*)ks;
      *(bf16x8*)&Klds[row][cs + 8] = *(const bf16x8*)(ks + 8);
      const unsigned short* vs = vbase + (size_t)(j0 + row) * 3072 + cs;
      B8 v0, v1;
      v0.v = *(const bf16x8*)vs;
      v1.v = *(const bf16x8*)(vs + 8);
      #pragma unroll
      for (int e = 0; e < 8; e++) {
        Vtlds[cs + e][row]     = v0.u[e];
        Vtlds[cs + 8 + e][row] = v1.u[e];
      }
      const int er = tid >> 1, ecs = (tid & 1) * 32;
      int rsrc = 960 - i0 + j0 + er;       // >= 0 always; clamp masked overrun
      if (rsrc > 1023) rsrc = 1023;
      const unsigned short* es = Er + (size_t)rsrc * 64 + ecs;
      *(bf16x8*)&Elds[er][ecs]      = *(const bf16x8*)es;
      *(bf16x8*)&Elds[er][ecs + 8]  = *(const bf16x8*)(es + 8);
      *(bf16x8*)&Elds[er][ecs + 16] = *(const bf16x8*)(es + 16);
      *(bf16x8*)&Elds[er][ecs + 24] = *(const bf16x8*)(es + 24);
    }
    __syncthreads();

    // ---- QK^T ----
    f32x4 S[4];
    #pragma unroll
    for (int nt = 0; nt < 4; nt++) {
      f32x4 a; a[0]=0.f; a[1]=0.f; a[2]=0.f; a[3]=0.f;
      bf16x8 k0 = *(const bf16x8*)&Klds[nt * 16 + c15][q * 8];
      bf16x8 k1 = *(const bf16x8*)&Klds[nt * 16 + c15][32 + q * 8];
      a = __builtin_amdgcn_mfma_f32_16x16x32_bf16(qf[0], k0, a, 0, 0, 0);
      a = __builtin_amdgcn_mfma_f32_16x16x32_bf16(qf[1], k1, a, 0, 0, 0);
      S[nt] = a;
    }

    // ---- C2 = q . Er-band (wave-windowed: 5 of 8 tiles), bf16 store ----
    #pragma unroll
    for (int t5 = 0; t5 < 5; t5++) {
      const int pt = 3 - w + t5;
      f32x4 a; a[0]=0.f; a[1]=0.f; a[2]=0.f; a[3]=0.f;
      bf16x8 e0 = *(const bf16x8*)&Elds[pt * 16 + c15][q * 8];
      bf16x8 e1 = *(const bf16x8*)&Elds[pt * 16 + c15][32 + q * 8];
      a = __builtin_amdgcn_mfma_f32_16x16x32_bf16(qf[0], e0, a, 0, 0, 0);
      a = __builtin_amdgcn_mfma_f32_16x16x32_bf16(qf[1], e1, a, 0, 0, 0);
      #pragma unroll
      for (int r = 0; r < 4; r++)
        c2w[(rowq + r) * 88 + t5 * 16 + c15] = f2bf(a[r]);
    }

    // ---- assemble scores: + Srel + structure bias, causal mask ----
    #pragma unroll
    for (int nt = 0; nt < 4; nt++) {
      const int j = j0 + nt * 16 + c15;
      int ii[4][4];
      #pragma unroll
      for (int r = 0; r < 4; r++) {
        const size_t off = idx0 + (size_t)r * 1024 + j;
        ii[r][0] = rbar[off]; ii[r][1] = rpos[off];
        ii[r][2] = roct[off]; ii[r][3] = rsem[off];
      }
      #pragma unroll
      for (int r = 0; r < 4; r++) {
        const float* qe = qe0 + (size_t)r * 152;
        const float bias = qe[ii[r][0]] + qe[17 + ii[r][1]] + qe[113 + ii[r][2]] + qe[138 + ii[r][3]];
        const float srel = bf2f(c2w[(rowq + r) * 88 + (15 - (rowq + r) + nt * 16 + c15)]);
        float sc = S[nt][r] + srel + bias;
        if (jt == it && j > iw + rowq + r) sc = -3e38f;  // causal
        S[nt][r] = sc;
      }
    }

    // ---- online softmax (row stats live at (quad,reg), replicated x16 lanes) ----
    float alpha[4];
    #pragma unroll
    for (int r = 0; r < 4; r++) {
      float v = fmaxf(fmaxf(S[0][r], S[1][r]), fmaxf(S[2][r], S[3][r]));
      v = fmaxf(v, __shfl_xor(v, 1));
      v = fmaxf(v, __shfl_xor(v, 2));
      v = fmaxf(v, __shfl_xor(v, 4));
      v = fmaxf(v, __shfl_xor(v, 8));
      const float mn = fmaxf(mrow[r], v);
      alpha[r] = __expf(mrow[r] - mn);
      mrow[r] = mn;
    }
    #pragma unroll
    for (int nt = 0; nt < 4; nt++)
      #pragma unroll
      for (int r = 0; r < 4; r++)
        S[nt][r] = __expf(S[nt][r] - mrow[r]);
    #pragma unroll
    for (int r = 0; r < 4; r++) {
      float s = S[0][r] + S[1][r] + S[2][r] + S[3][r];
      s += __shfl_xor(s, 1);
      s += __shfl_xor(s, 2);
      s += __shfl_xor(s, 4);
      s += __shfl_xor(s, 8);
      lrow[r] = lrow[r] * alpha[r] + s;
      #pragma unroll
      for (int dt = 0; dt < 4; dt++) Oa[dt][r] *= alpha[r];
    }

    // ---- P round-trip through per-wave LDS (bf16; read is ds_read_b128) ----
    #pragma unroll
    for (int nt = 0; nt < 4; nt++)
      #pragma unroll
      for (int r = 0; r < 4; r++)
        c2w[(rowq + r) * 88 + nt * 16 + c15] = f2bf(S[nt][r]);

    bf16x8 pf[2];
    #pragma unroll
    for (int kk = 0; kk < 2; kk++)
      pf[kk] = *(const bf16x8*)&c2w[c15 * 88 + kk * 32 + q * 8];

    // ---- O += P @ V ----
    #pragma unroll
    for (int dt = 0; dt < 4; dt++) {
      bf16x8 v0 = *(const bf16x8*)&Vtlds[dt * 16 + c15][q * 8];
      bf16x8 v1 = *(const bf16x8*)&Vtlds[dt * 16 + c15][32 + q * 8];
      Oa[dt] = __builtin_amdgcn_mfma_f32_16x16x32_bf16(pf[0], v0, Oa[dt], 0, 0, 0);
      Oa[dt] = __builtin_amdgcn_mfma_f32_16x16x32_bf16(pf[1], v1, Oa[dt], 0, 0, 0);
    }
  }

  // ---- epilogue: O / l -> Ob (b, i, h*64+d) bf16, row stride 1024 ----
  #pragma unroll
  for (int dt = 0; dt < 4; dt++)
    #pragma unroll
    for (int r = 0; r < 4; r++) {
      const int i_ = iw + rowq + r;
      const float o = Oa[dt][r] / lrow[r];
      Ob[((size_t)bb * 1024 + i_) * 1024 + h * 64 + dt * 16 + c15] = f2bf(o);
    }
}

// ---------------------------------------------------------------------------
extern "C" void kernel_launch(void* const* d_in, const int* in_sizes, int n_in,
                              void* d_out, int out_size, void* d_ws, size_t ws_size,
                              hipStream_t stream)
{
  const float* x    = (const float*)d_in[0];
  const int*   rbar = (const int*)d_in[1];
  const int*   rpos = (const int*)d_in[2];
  const int*   roct = (const int*)d_in[3];
  const int*   rsem = (const int*)d_in[4];
  const float* Wq   = (const float*)d_in[5];
  const float* Wk   = (const float*)d_in[6];
  const float* Wv   = (const float*)d_in[7];
  const float* Wo   = (const float*)d_in[8];
  const float* Er   = (const float*)d_in[9];
  const float* Tb   = (const float*)d_in[10];
  const float* Tp   = (const float*)d_in[11];
  const float* To   = (const float*)d_in[12];
  const float* Ts   = (const float*)d_in[13];
  float* out = (float*)d_out;

  // workspace layout (~49 MB)
  char* ws = (char*)d_ws;
  const size_t MB = 1u << 20;
  unsigned short* x_bf    = (unsigned short*)(ws);            // 4 MB
  unsigned short* Wqkv_bf = (unsigned short*)(ws + 4 * MB);   // 6 MB (Wq|Wk|Wv rows)
  unsigned short* Wo_bf   = (unsigned short*)(ws + 10 * MB);  // 2 MB
  unsigned short* Er_bf   = (unsigned short*)(ws + 12 * MB);  // 128 KB
  unsigned short* QKVb    = (unsigned short*)(ws + 13 * MB);  // 12 MB
  unsigned short* Ob      = (unsigned short*)(ws + 25 * MB);  // 4 MB
  float*          QE      = (float*)(ws + 29 * MB);           // 19.9 MB

  cast_f32_bf16<<<1024, 256, 0, stream>>>(x,  x_bf,  2 * 1024 * 1024);
  cast_f32_bf16<<<1024, 256, 0, stream>>>(Wq, Wqkv_bf,               1024 * 1024);
  cast_f32_bf16<<<1024, 256, 0, stream>>>(Wk, Wqkv_bf + 1024 * 1024, 1024 * 1024);
  cast_f32_bf16<<<1024, 256, 0, stream>>>(Wv, Wqkv_bf + 2048 * 1024, 1024 * 1024);
  cast_f32_bf16<<<1024, 256, 0, stream>>>(Wo, Wo_bf, 1024 * 1024);
  cast_f32_bf16<<<64,   256, 0, stream>>>(Er, Er_bf, 1024 * 64);

  // fused QKV projection: (2048 x 3072) = x (2048 x 1024) @ Wqkv^T
  gemm128<false><<<dim3(24, 16), 256, 0, stream>>>(x_bf, Wqkv_bf, QKVb, 2048, 3072, 1024);
  qe_kernel<<<2048, 256, 0, stream>>>(QKVb, Tb, Tp, To, Ts, QE);
  attn_kernel<<<dim3(16, 16, 2), 256, 0, stream>>>(QKVb, QE,
                                                   rbar, rpos, roct, rsem, Er_bf, Ob);
  gemm128<true><<<dim3(8, 16), 256, 0, stream>>>(Ob, Wo_bf, out, 2048, 1024, 1024);
}

// Round 4
// 326.262 us; speedup vs baseline: 1.4491x; 1.2820x over previous
//
#include <hip/hip_runtime.h>

// ---------------------------------------------------------------------------
// RelativeStructureAttention (Music-Transformer style) on MI355X / gfx950.
//   b=2, n=1024, dim=1024, HEADS=16, d_h=64. Inputs fp32 (+int32 idx), out fp32.
// Pipeline:
//   0) cast_all   x,[Wq|Wk|Wv],Wo,Er -> bf16 in ws (one fused kernel)
//      pack_idx   4 idx arrays -> 1 uint32 with pre-based offsets
//   1) gemm128<2> x@Wqkv^T -> QKVh  (bf16, HEAD-MAJOR (which,b,h,n,64))
//   2) qe_kernel  per (b,i): 151x16 dots q.table/8 -> QE fp16 (stride 152)
//   3) attn       flash attention, paired i-tiles (p,15-p): 17 iters/block,
//                 QE rows staged in LDS, packed idx, Er frags from global
//   4) gemm128<1> O@Wo^T -> d_out (fp32)
// ---------------------------------------------------------------------------

using bf16x8 = __attribute__((ext_vector_type(8))) short;
using f32x4  = __attribute__((ext_vector_type(4))) float;

__device__ __forceinline__ float bf2f(unsigned short u) {
  unsigned x = ((unsigned)u) << 16;
  float f;
  __builtin_memcpy(&f, &x, 4);
  return f;
}
__device__ __forceinline__ unsigned short f2bf(float f) {
  unsigned x;
  __builtin_memcpy(&x, &f, 4);
  unsigned r = (x + 0x7FFFu + ((x >> 16) & 1u)) >> 16;  // round-nearest-even
  return (unsigned short)r;
}

union B8 { bf16x8 v; unsigned short u[8]; };

// ---------------------------------------------------------------------------
// fused fp32 -> bf16 cast of all six tensors (region table in float4 units)
// ---------------------------------------------------------------------------
__global__ __launch_bounds__(256) void cast_all(
    const float* __restrict__ x,  const float* __restrict__ Wq,
    const float* __restrict__ Wk, const float* __restrict__ Wv,
    const float* __restrict__ Wo, const float* __restrict__ Er,
    unsigned short* __restrict__ x_bf, unsigned short* __restrict__ Wqkv,
    unsigned short* __restrict__ Wo_bf, unsigned short* __restrict__ Er_bf)
{
  const int total = 1589248;  // 6,356,992 floats / 4
  for (int i = blockIdx.x * 256 + threadIdx.x; i < total; i += gridDim.x * 256) {
    const float4* s4;
    ushort4* d4;
    if (i < 524288)       { s4 = (const float4*)x  + i;           d4 = (ushort4*)x_bf  + i; }
    else if (i < 786432)  { s4 = (const float4*)Wq + (i-524288);  d4 = (ushort4*)Wqkv  + (i-524288); }
    else if (i < 1048576) { s4 = (const float4*)Wk + (i-786432);  d4 = (ushort4*)Wqkv  + (i-786432) + 262144; }
    else if (i < 1310720) { s4 = (const float4*)Wv + (i-1048576); d4 = (ushort4*)Wqkv  + (i-1048576) + 524288; }
    else if (i < 1572864) { s4 = (const float4*)Wo + (i-1310720); d4 = (ushort4*)Wo_bf + (i-1310720); }
    else                  { s4 = (const float4*)Er + (i-1572864); d4 = (ushort4*)Er_bf + (i-1572864); }
    const float4 v = *s4;
    ushort4 o;
    o.x = f2bf(v.x); o.y = f2bf(v.y); o.z = f2bf(v.z); o.w = f2bf(v.w);
    *d4 = o;
  }
}

// ---------------------------------------------------------------------------
// pack 4 structure indices into one uint32 with pre-added QE-row bases:
//   bar | (17+pos)<<5 | (113+oct)<<12 | (138+sem)<<20
// ---------------------------------------------------------------------------
__global__ __launch_bounds__(256) void pack_idx(
    const int* __restrict__ rb, const int* __restrict__ rp,
    const int* __restrict__ ro, const int* __restrict__ rs,
    unsigned* __restrict__ o, int n4)
{
  for (int i = blockIdx.x * 256 + threadIdx.x; i < n4; i += gridDim.x * 256) {
    const int4 a = ((const int4*)rb)[i];
    const int4 b = ((const int4*)rp)[i];
    const int4 c = ((const int4*)ro)[i];
    const int4 d = ((const int4*)rs)[i];
    uint4 r;
    r.x = (unsigned)(a.x | (17+b.x)<<5 | (113+c.x)<<12 | (138+d.x)<<20);
    r.y = (unsigned)(a.y | (17+b.y)<<5 | (113+c.y)<<12 | (138+d.y)<<20);
    r.z = (unsigned)(a.z | (17+b.z)<<5 | (113+c.z)<<12 | (138+d.z)<<20);
    r.w = (unsigned)(a.w | (17+b.w)<<5 | (113+c.w)<<12 | (138+d.w)<<20);
    ((uint4*)o)[i] = r;
  }
}

// ---------------------------------------------------------------------------
// m97-style GEMM: C[m][n] = sum_k A[m][k]*B[n][k]; 128x128 tile, BK=32,
// global_load_lds width 16, 2-barrier K-loop, 4 waves 2x2, 4x4 MFMA/wave.
// MODE 0: bf16 row-major out; 1: f32 row-major out;
//      2: bf16 QKV head-major scatter (which = n>>10, h = (n>>6)&15, d = n&63)
// ---------------------------------------------------------------------------
__device__ __forceinline__ void ld_lds16(const unsigned short* g, unsigned short* l) {
  __builtin_amdgcn_global_load_lds(
      (const __attribute__((address_space(1))) unsigned int*)g,
      (__attribute__((address_space(3))) unsigned int*)l, 16, 0, 0);
}

template <int MODE>
__global__ __launch_bounds__(256) void gemm128(const unsigned short* __restrict__ A,
                                               const unsigned short* __restrict__ B,
                                               void* __restrict__ Cv,
                                               int M, int N, int K)
{
  __shared__ __align__(16) unsigned short Atile[128 * 32];
  __shared__ __align__(16) unsigned short Btile[128 * 32];
  const int tid = threadIdx.x;
  const int w = tid >> 6, lane = tid & 63;
  const int c15 = lane & 15, q = lane >> 4;
  const int wr = w >> 1, wc = w & 1;
  const int n0 = blockIdx.x * 128, m0 = blockIdx.y * 128;

  const unsigned short* ag = A + (size_t)(m0 + (tid >> 2)) * K + (tid & 3) * 8;
  const unsigned short* bg = B + (size_t)(n0 + (tid >> 2)) * K + (tid & 3) * 8;
  unsigned short* al = &Atile[tid * 8];
  unsigned short* bl = &Btile[tid * 8];
  const size_t half = (size_t)64 * K;

  f32x4 acc[4][4];
  #pragma unroll
  for (int mt = 0; mt < 4; mt++)
    #pragma unroll
    for (int nt = 0; nt < 4; nt++) { acc[mt][nt][0]=0.f; acc[mt][nt][1]=0.f; acc[mt][nt][2]=0.f; acc[mt][nt][3]=0.f; }

  for (int k0 = 0; k0 < K; k0 += 32) {
    __syncthreads();
    ld_lds16(ag + k0, al);
    ld_lds16(ag + half + k0, al + 2048);
    ld_lds16(bg + k0, bl);
    ld_lds16(bg + half + k0, bl + 2048);
    __syncthreads();

    bf16x8 af[4], bfr[4];
    #pragma unroll
    for (int mt = 0; mt < 4; mt++)
      af[mt] = *(const bf16x8*)&Atile[(wr * 64 + mt * 16 + c15) * 32 + q * 8];
    #pragma unroll
    for (int nt = 0; nt < 4; nt++)
      bfr[nt] = *(const bf16x8*)&Btile[(wc * 64 + nt * 16 + c15) * 32 + q * 8];
    #pragma unroll
    for (int mt = 0; mt < 4; mt++)
      #pragma unroll
      for (int nt = 0; nt < 4; nt++)
        acc[mt][nt] = __builtin_amdgcn_mfma_f32_16x16x32_bf16(af[mt], bfr[nt], acc[mt][nt], 0, 0, 0);
  }

  #pragma unroll
  for (int mt = 0; mt < 4; mt++)
    #pragma unroll
    for (int nt = 0; nt < 4; nt++)
      #pragma unroll
      for (int r = 0; r < 4; r++) {
        const int m = m0 + wr * 64 + mt * 16 + q * 4 + r;
        const int n = n0 + wc * 64 + nt * 16 + c15;
        if constexpr (MODE == 1) {
          ((float*)Cv)[(size_t)m * N + n] = acc[mt][nt][r];
        } else if constexpr (MODE == 0) {
          ((unsigned short*)Cv)[(size_t)m * N + n] = f2bf(acc[mt][nt][r]);
        } else {
          const int which = n >> 10, hh = (n >> 6) & 15, d = n & 63;
          const int bb = m >> 10, i = m & 1023;
          ((unsigned short*)Cv)[(size_t)which * 2097152 +
                                (((size_t)(bb << 4) + hh) << 16) + (i << 6) + d] = f2bf(acc[mt][nt][r]);
        }
      }
}

// ---------------------------------------------------------------------------
// QE[b,h,i,s] = 0.125 * dot(q[b,h,i,:], table_row(s))  (fp16 out, stride 152)
// s layout: [0..16]=bar(16+zero), [17..112]=pos(95+zero),
//           [113..137]=oct(24+zero), [138..150]=sem(12+zero).
// grid = b*n blocks; Q read head-major from QKVh.
// ---------------------------------------------------------------------------
__global__ __launch_bounds__(256) void qe_kernel(
    const unsigned short* __restrict__ Qh,
    const float* __restrict__ Tb, const float* __restrict__ Tp,
    const float* __restrict__ To, const float* __restrict__ Ts,
    _Float16* __restrict__ QE)
{
  __shared__ float qrow[1024];
  __shared__ float tbl[147][65];  // +1 pad: avoids 64-stride bank conflicts
  const int bb = blockIdx.x >> 10;
  const int i  = blockIdx.x & 1023;
  const int tid = threadIdx.x;

  for (int t = tid; t < 1024; t += 256) {
    const int h = t >> 6, d = t & 63;
    qrow[t] = bf2f(Qh[(((size_t)(bb << 4) + h) << 16) + (i << 6) + d]);
  }
  for (int t = tid; t < 147 * 64; t += 256) {
    const int r = t >> 6, d = t & 63;
    float v;
    if (r < 16)       v = Tb[r * 64 + d];
    else if (r < 111) v = Tp[(r - 16) * 64 + d];
    else if (r < 135) v = To[(r - 111) * 64 + d];
    else              v = Ts[(r - 135) * 64 + d];
    tbl[r][d] = v;
  }
  __syncthreads();

  for (int t = tid; t < 151 * 16; t += 256) {
    const int h = t / 151;
    const int s = t - h * 151;
    int row;
    if (s < 17)       row = (s < 16)  ? s               : -1;
    else if (s < 113) row = (s < 112) ? 16 + (s - 17)   : -1;
    else if (s < 138) row = (s < 137) ? 111 + (s - 113) : -1;
    else              row = (s < 150) ? 135 + (s - 138) : -1;
    float acc = 0.f;
    if (row >= 0) {
      #pragma unroll 8
      for (int d = 0; d < 64; d++) acc += qrow[h * 64 + d] * tbl[row][d];
    }
    QE[(((size_t)(bb << 4) + h) * 1024 + i) * 152 + s] = (_Float16)(0.125f * acc);
  }
}

// ---------------------------------------------------------------------------
// Flash attention. grid (h=16, pair=8, b=2) = 256 blocks; block 256 = 4 waves.
// Each block runs two i-tiles {p, 15-p} sequentially -> 17 jt iters, uniform.
// LDS 48 KB: Klds/Vtlds (+8 pad), per-wave C2 (bf16, stride 88), QE rows fp16.
// Srel[i,j] = q_i . Er[1023-i+j]: C2[m][L] via MFMA with Er B-frags read from
// GLOBAL (L1-resident band); wave w computes tiles pt=3-w..7-w, readback at
// L = 15-m+jj. Structure bias: packed idx (1 coalesced dword) + 4 ds_read_u16
// gathers from the LDS-staged QE rows.
// ---------------------------------------------------------------------------
__global__ __launch_bounds__(256) void attn_kernel(
    const unsigned short* __restrict__ QKVh,  // head-major: Q | K | V
    const _Float16* __restrict__ QE,
    const unsigned* __restrict__ Pidx,
    const unsigned short* __restrict__ Er,
    unsigned short* __restrict__ Ob)
{
  const int h  = blockIdx.x;
  const int pp = blockIdx.y;
  const int bb = blockIdx.z;
  const int tid = threadIdx.x;
  const int w = tid >> 6;
  const int lane = tid & 63;
  const int c15 = lane & 15;
  const int q = lane >> 4;
  const int rowq = q * 4;

  __shared__ __align__(16) unsigned short Klds[64][72];
  __shared__ __align__(16) unsigned short Vtlds[64][72];   // V transposed: [d][j]
  __shared__ __align__(16) unsigned short C2[4][16 * 88];  // per-wave scratch (bf16)
  __shared__ __align__(16) _Float16 qeh[64 * 152];         // QE rows for this i-tile
  unsigned short* c2w = &C2[w][0];

  const unsigned short* qhb = QKVh + (((size_t)(bb << 4) + h) << 16);
  const unsigned short* khb = qhb + 2097152;
  const unsigned short* vhb = qhb + 2 * 2097152;

  for (int ph = 0; ph < 2; ph++) {
    const int it = ph ? (15 - pp) : pp;
    const int i0 = it << 6;
    const int iw = i0 + w * 16;

    __syncthreads();  // prev phase done with qeh/LDS

    // ---- stage QE rows (flat fp16 copy, 9728 halves) ----
    {
      const size_t qeoff = (((size_t)(bb << 4) + h) * 1024 + i0) * 152;
      const unsigned short* src = (const unsigned short*)QE + qeoff;
      for (int t = tid; t < 9728; t += 256)
        ((unsigned short*)qeh)[t] = src[t];
    }

    // ---- Q fragments, pre-scaled by 1/sqrt(d)=1/8 ----
    bf16x8 qf[2];
    {
      const unsigned short* qp = qhb + ((size_t)(i0 + w * 16 + c15) << 6);
      #pragma unroll
      for (int kk = 0; kk < 2; kk++) {
        B8 t;
        t.v = *(const bf16x8*)(qp + kk * 32 + q * 8);
        #pragma unroll
        for (int e = 0; e < 8; e++) t.u[e] = f2bf(bf2f(t.u[e]) * 0.125f);
        qf[kk] = t.v;
      }
    }

    f32x4 Oa[4];
    float mrow[4], lrow[4];
    #pragma unroll
    for (int dt = 0; dt < 4; dt++) { Oa[dt][0]=0.f; Oa[dt][1]=0.f; Oa[dt][2]=0.f; Oa[dt][3]=0.f; }
    #pragma unroll
    for (int r = 0; r < 4; r++) { mrow[r] = -3e38f; lrow[r] = 0.f; }

    const size_t idx0 = ((size_t)bb << 20) + ((size_t)(iw + rowq) << 10);

    for (int jt = 0; jt <= it; jt++) {
      const int j0 = jt << 6;
      __syncthreads();  // prev iter's LDS consumers done

      // ---- stage K (contiguous 8 KB) and V^T ----
      {
        const unsigned short* kt = khb + (j0 << 6);
        *(bf16x8*)&Klds[tid >> 3][(tid & 7) * 8]        = *(const bf16x8*)(kt + tid * 8);
        *(bf16x8*)&Klds[32 + (tid >> 3)][(tid & 7) * 8] = *(const bf16x8*)(kt + 2048 + tid * 8);
        const int vrow = tid >> 2, vcs = (tid & 3) * 16;
        const unsigned short* vt = vhb + (j0 << 6) + (vrow << 6) + vcs;
        B8 v0, v1;
        v0.v = *(const bf16x8*)vt;
        v1.v = *(const bf16x8*)(vt + 8);
        #pragma unroll
        for (int e = 0; e < 8; e++) {
          Vtlds[vcs + e][vrow]     = v0.u[e];
          Vtlds[vcs + 8 + e][vrow] = v1.u[e];
        }
      }
      __syncthreads();

      // ---- QK^T ----
      f32x4 S[4];
      #pragma unroll
      for (int nt = 0; nt < 4; nt++) {
        f32x4 a; a[0]=0.f; a[1]=0.f; a[2]=0.f; a[3]=0.f;
        bf16x8 k0 = *(const bf16x8*)&Klds[nt * 16 + c15][q * 8];
        bf16x8 k1 = *(const bf16x8*)&Klds[nt * 16 + c15][32 + q * 8];
        a = __builtin_amdgcn_mfma_f32_16x16x32_bf16(qf[0], k0, a, 0, 0, 0);
        a = __builtin_amdgcn_mfma_f32_16x16x32_bf16(qf[1], k1, a, 0, 0, 0);
        S[nt] = a;
      }

      // ---- C2 = q . Er-band (Er B-frags from global; 5 of 8 tiles/wave) ----
      {
        const int rbase = 960 - i0 + j0;
        #pragma unroll
        for (int t5 = 0; t5 < 5; t5++) {
          const int pt = 3 - w + t5;
          int row = rbase + pt * 16 + c15;
          row = row > 1023 ? 1023 : row;   // masked-region overrun clamp
          const unsigned short* ep = Er + (row << 6) + q * 8;
          bf16x8 e0 = *(const bf16x8*)ep;
          bf16x8 e1 = *(const bf16x8*)(ep + 32);
          f32x4 a; a[0]=0.f; a[1]=0.f; a[2]=0.f; a[3]=0.f;
          a = __builtin_amdgcn_mfma_f32_16x16x32_bf16(qf[0], e0, a, 0, 0, 0);
          a = __builtin_amdgcn_mfma_f32_16x16x32_bf16(qf[1], e1, a, 0, 0, 0);
          #pragma unroll
          for (int r = 0; r < 4; r++)
            c2w[(rowq + r) * 88 + t5 * 16 + c15] = f2bf(a[r]);
        }
      }

      // ---- scores: + Srel + structure bias (LDS gathers), causal mask ----
      #pragma unroll
      for (int nt = 0; nt < 4; nt++) {
        const int j = j0 + nt * 16 + c15;
        unsigned pv[4];
        #pragma unroll
        for (int r = 0; r < 4; r++)
          pv[r] = Pidx[idx0 + ((size_t)r << 10) + j];
        #pragma unroll
        for (int r = 0; r < 4; r++) {
          const int rb = (w * 16 + rowq + r) * 152;
          const float bias = (float)qeh[rb + (pv[r] & 31)]
                           + (float)qeh[rb + ((pv[r] >> 5) & 127)]
                           + (float)qeh[rb + ((pv[r] >> 12) & 255)]
                           + (float)qeh[rb + (pv[r] >> 20)];
          const float srel = bf2f(c2w[(rowq + r) * 88 + (15 - (rowq + r) + nt * 16 + c15)]);
          float sc = S[nt][r] + srel + bias;
          if (jt == it && j > iw + rowq + r) sc = -3e38f;  // causal
          S[nt][r] = sc;
        }
      }

      // ---- online softmax ----
      float alpha[4];
      #pragma unroll
      for (int r = 0; r < 4; r++) {
        float v = fmaxf(fmaxf(S[0][r], S[1][r]), fmaxf(S[2][r], S[3][r]));
        v = fmaxf(v, __shfl_xor(v, 1));
        v = fmaxf(v, __shfl_xor(v, 2));
        v = fmaxf(v, __shfl_xor(v, 4));
        v = fmaxf(v, __shfl_xor(v, 8));
        const float mn = fmaxf(mrow[r], v);
        alpha[r] = __expf(mrow[r] - mn);
        mrow[r] = mn;
      }
      #pragma unroll
      for (int nt = 0; nt < 4; nt++)
        #pragma unroll
        for (int r = 0; r < 4; r++)
          S[nt][r] = __expf(S[nt][r] - mrow[r]);
      #pragma unroll
      for (int r = 0; r < 4; r++) {
        float s = S[0][r] + S[1][r] + S[2][r] + S[3][r];
        s += __shfl_xor(s, 1);
        s += __shfl_xor(s, 2);
        s += __shfl_xor(s, 4);
        s += __shfl_xor(s, 8);
        lrow[r] = lrow[r] * alpha[r] + s;
        #pragma unroll
        for (int dt = 0; dt < 4; dt++) Oa[dt][r] *= alpha[r];
      }

      // ---- P round-trip through per-wave LDS (bf16, ds_read_b128 back) ----
      #pragma unroll
      for (int nt = 0; nt < 4; nt++)
        #pragma unroll
        for (int r = 0; r < 4; r++)
          c2w[(rowq + r) * 88 + nt * 16 + c15] = f2bf(S[nt][r]);

      bf16x8 pf[2];
      #pragma unroll
      for (int kk = 0; kk < 2; kk++)
        pf[kk] = *(const bf16x8*)&c2w[c15 * 88 + kk * 32 + q * 8];

      // ---- O += P @ V ----
      #pragma unroll
      for (int dt = 0; dt < 4; dt++) {
        bf16x8 v0 = *(const bf16x8*)&Vtlds[dt * 16 + c15][q * 8];
        bf16x8 v1 = *(const bf16x8*)&Vtlds[dt * 16 + c15][32 + q * 8];
        Oa[dt] = __builtin_amdgcn_mfma_f32_16x16x32_bf16(pf[0], v0, Oa[dt], 0, 0, 0);
        Oa[dt] = __builtin_amdgcn_mfma_f32_16x16x32_bf16(pf[1], v1, Oa[dt], 0, 0, 0);
      }
    }

    // ---- epilogue: O / l -> Ob (b, i, h*64+d) bf16 ----
    #pragma unroll
    for (int dt = 0; dt < 4; dt++)
      #pragma unroll
      for (int r = 0; r < 4; r++) {
        const int i_ = iw + rowq + r;
        const float o = Oa[dt][r] / lrow[r];
        Ob[(((size_t)bb << 10) + i_) * 1024 + h * 64 + dt * 16 + c15] = f2bf(o);
      }
  }
}

// ---------------------------------------------------------------------------
extern "C" void kernel_launch(void* const* d_in, const int* in_sizes, int n_in,
                              void* d_out, int out_size, void* d_ws, size_t ws_size,
                              hipStream_t stream)
{
  const float* x    = (const float*)d_in[0];
  const int*   rbar = (const int*)d_in[1];
  const int*   rpos = (const int*)d_in[2];
  const int*   roct = (const int*)d_in[3];
  const int*   rsem = (const int*)d_in[4];
  const float* Wq   = (const float*)d_in[5];
  const float* Wk   = (const float*)d_in[6];
  const float* Wv   = (const float*)d_in[7];
  const float* Wo   = (const float*)d_in[8];
  const float* Er   = (const float*)d_in[9];
  const float* Tb   = (const float*)d_in[10];
  const float* Tp   = (const float*)d_in[11];
  const float* To   = (const float*)d_in[12];
  const float* Ts   = (const float*)d_in[13];
  float* out = (float*)d_out;

  // workspace layout (~47 MB)
  char* ws = (char*)d_ws;
  const size_t MB = 1u << 20;
  unsigned short* x_bf    = (unsigned short*)(ws);            //  4 MB
  unsigned short* Wqkv_bf = (unsigned short*)(ws + 4 * MB);   //  6 MB
  unsigned short* Wo_bf   = (unsigned short*)(ws + 10 * MB);  //  2 MB
  unsigned short* Er_bf   = (unsigned short*)(ws + 12 * MB);  //  128 KB
  unsigned short* QKVh    = (unsigned short*)(ws + 13 * MB);  // 12 MB (head-major Q|K|V)
  unsigned short* Ob      = (unsigned short*)(ws + 25 * MB);  //  4 MB
  _Float16*       QE      = (_Float16*)(ws + 29 * MB);        //  9.5 MB
  unsigned*       Pidx    = (unsigned*)(ws + 39 * MB);        //  8 MB

  cast_all<<<1024, 256, 0, stream>>>(x, Wq, Wk, Wv, Wo, Er, x_bf, Wqkv_bf, Wo_bf, Er_bf);
  pack_idx<<<1024, 256, 0, stream>>>(rbar, rpos, roct, rsem, Pidx, 524288);

  // fused QKV projection with head-major scatter
  gemm128<2><<<dim3(24, 16), 256, 0, stream>>>(x_bf, Wqkv_bf, QKVh, 2048, 3072, 1024);
  qe_kernel<<<2048, 256, 0, stream>>>(QKVh, Tb, Tp, To, Ts, QE);
  attn_kernel<<<dim3(16, 8, 2), 256, 0, stream>>>(QKVh, QE, Pidx, Er_bf, Ob);
  gemm128<1><<<dim3(8, 16), 256, 0, stream>>>(Ob, Wo_bf, out, 2048, 1024, 1024);
}

// Round 7
// 269.872 us; speedup vs baseline: 1.7518x; 1.2090x over previous
//
#include <hip/hip_runtime.h>

// ---------------------------------------------------------------------------
// RelativeStructureAttention (Music-Transformer style) on MI355X / gfx950.
//   b=2, n=1024, dim=1024, HEADS=16, d_h=64. Inputs fp32 (+int32 idx), out fp32.
// Pipeline (round 7 = round 4 passing structure + grid fix + MFMA qe):
//   0) cast_all   x,[Wq|Wk|Wv],Wo,Er -> bf16; build_tpad 160x64 bf16 *0.125;
//      pack_idx   4 idx arrays -> 1 uint32 with pre-based offsets
//   1) gemm128<2> x@Wqkv^T -> QKVh (bf16, head-major (which,b,h,n,64))
//   2) qe_gemm    QE[(bh,i),s] = Qrow . Tpad[s]  (fp16, stride 160) via MFMA
//   3) attn       flash attention, ROUND-4 BODY (2-barrier jt loop, 64-row
//                 block, K/V LDS staging); grid 512 unpaired, it flipped for
//                 bb==1 so co-resident blocks form (long,short) pairs
//   4) gemm128<1> O@Wo^T -> d_out (fp32)
// ---------------------------------------------------------------------------

using bf16x8 = __attribute__((ext_vector_type(8))) short;
using f32x4  = __attribute__((ext_vector_type(4))) float;

__device__ __forceinline__ float bf2f(unsigned short u) {
  unsigned x = ((unsigned)u) << 16;
  float f;
  __builtin_memcpy(&f, &x, 4);
  return f;
}
__device__ __forceinline__ unsigned short f2bf(float f) {
  unsigned x;
  __builtin_memcpy(&x, &f, 4);
  unsigned r = (x + 0x7FFFu + ((x >> 16) & 1u)) >> 16;  // round-nearest-even
  return (unsigned short)r;
}

union B8 { bf16x8 v; unsigned short u[8]; };

// ---------------------------------------------------------------------------
// fused fp32 -> bf16 cast of all six tensors (region table in float4 units)
// ---------------------------------------------------------------------------
__global__ __launch_bounds__(256) void cast_all(
    const float* __restrict__ x,  const float* __restrict__ Wq,
    const float* __restrict__ Wk, const float* __restrict__ Wv,
    const float* __restrict__ Wo, const float* __restrict__ Er,
    unsigned short* __restrict__ x_bf, unsigned short* __restrict__ Wqkv,
    unsigned short* __restrict__ Wo_bf, unsigned short* __restrict__ Er_bf)
{
  const int total = 1589248;  // 6,356,992 floats / 4
  for (int i = blockIdx.x * 256 + threadIdx.x; i < total; i += gridDim.x * 256) {
    const float4* s4;
    ushort4* d4;
    if (i < 524288)       { s4 = (const float4*)x  + i;           d4 = (ushort4*)x_bf  + i; }
    else if (i < 786432)  { s4 = (const float4*)Wq + (i-524288);  d4 = (ushort4*)Wqkv  + (i-524288); }
    else if (i < 1048576) { s4 = (const float4*)Wk + (i-786432);  d4 = (ushort4*)Wqkv  + (i-786432) + 262144; }
    else if (i < 1310720) { s4 = (const float4*)Wv + (i-1048576); d4 = (ushort4*)Wqkv  + (i-1048576) + 524288; }
    else if (i < 1572864) { s4 = (const float4*)Wo + (i-1310720); d4 = (ushort4*)Wo_bf + (i-1310720); }
    else                  { s4 = (const float4*)Er + (i-1572864); d4 = (ushort4*)Er_bf + (i-1572864); }
    const float4 v = *s4;
    ushort4 o;
    o.x = f2bf(v.x); o.y = f2bf(v.y); o.z = f2bf(v.z); o.w = f2bf(v.w);
    *d4 = o;
  }
}

// padded structure table, pre-scaled by 1/8:
//  s: [0..15]=bar, 16=0, [17..111]=pos, 112=0, [113..136]=oct, 137=0,
//     [138..149]=sem, 150..159=0
__global__ __launch_bounds__(256) void build_tpad(
    const float* __restrict__ Tb, const float* __restrict__ Tp,
    const float* __restrict__ To, const float* __restrict__ Ts,
    unsigned short* __restrict__ Tpad)
{
  const int t = blockIdx.x * 256 + threadIdx.x;
  if (t >= 10240) return;
  const int s = t >> 6, d = t & 63;
  float v = 0.f;
  if (s < 16)       v = Tb[s * 64 + d];
  else if (s == 16) v = 0.f;
  else if (s < 112) v = Tp[(s - 17) * 64 + d];
  else if (s < 113) v = 0.f;
  else if (s < 137) v = To[(s - 113) * 64 + d];
  else if (s < 138) v = 0.f;
  else if (s < 150) v = Ts[(s - 138) * 64 + d];
  Tpad[t] = f2bf(v * 0.125f);
}

// pack 4 structure indices: bar | (17+pos)<<5 | (113+oct)<<12 | (138+sem)<<20
__global__ __launch_bounds__(256) void pack_idx(
    const int* __restrict__ rb, const int* __restrict__ rp,
    const int* __restrict__ ro, const int* __restrict__ rs,
    unsigned* __restrict__ o, int n4)
{
  for (int i = blockIdx.x * 256 + threadIdx.x; i < n4; i += gridDim.x * 256) {
    const int4 a = ((const int4*)rb)[i];
    const int4 b = ((const int4*)rp)[i];
    const int4 c = ((const int4*)ro)[i];
    const int4 d = ((const int4*)rs)[i];
    uint4 r;
    r.x = (unsigned)(a.x | (17+b.x)<<5 | (113+c.x)<<12 | (138+d.x)<<20);
    r.y = (unsigned)(a.y | (17+b.y)<<5 | (113+c.y)<<12 | (138+d.y)<<20);
    r.z = (unsigned)(a.z | (17+b.z)<<5 | (113+c.z)<<12 | (138+d.z)<<20);
    r.w = (unsigned)(a.w | (17+b.w)<<5 | (113+c.w)<<12 | (138+d.w)<<20);
    ((uint4*)o)[i] = r;
  }
}

// ---------------------------------------------------------------------------
// m97-style GEMM. MODE 1: f32 row-major out; 2: bf16 QKV head-major scatter.
// ---------------------------------------------------------------------------
__device__ __forceinline__ void ld_lds16(const unsigned short* g, unsigned short* l) {
  __builtin_amdgcn_global_load_lds(
      (const __attribute__((address_space(1))) unsigned int*)g,
      (__attribute__((address_space(3))) unsigned int*)l, 16, 0, 0);
}

template <int MODE>
__global__ __launch_bounds__(256) void gemm128(const unsigned short* __restrict__ A,
                                               const unsigned short* __restrict__ B,
                                               void* __restrict__ Cv,
                                               int M, int N, int K)
{
  __shared__ __align__(16) unsigned short Atile[128 * 32];
  __shared__ __align__(16) unsigned short Btile[128 * 32];
  const int tid = threadIdx.x;
  const int w = tid >> 6, lane = tid & 63;
  const int c15 = lane & 15, q = lane >> 4;
  const int wr = w >> 1, wc = w & 1;
  const int n0 = blockIdx.x * 128, m0 = blockIdx.y * 128;

  const unsigned short* ag = A + (size_t)(m0 + (tid >> 2)) * K + (tid & 3) * 8;
  const unsigned short* bg = B + (size_t)(n0 + (tid >> 2)) * K + (tid & 3) * 8;
  unsigned short* al = &Atile[tid * 8];
  unsigned short* bl = &Btile[tid * 8];
  const size_t half = (size_t)64 * K;

  f32x4 acc[4][4];
  #pragma unroll
  for (int mt = 0; mt < 4; mt++)
    #pragma unroll
    for (int nt = 0; nt < 4; nt++) { acc[mt][nt][0]=0.f; acc[mt][nt][1]=0.f; acc[mt][nt][2]=0.f; acc[mt][nt][3]=0.f; }

  for (int k0 = 0; k0 < K; k0 += 32) {
    __syncthreads();
    ld_lds16(ag + k0, al);
    ld_lds16(ag + half + k0, al + 2048);
    ld_lds16(bg + k0, bl);
    ld_lds16(bg + half + k0, bl + 2048);
    __syncthreads();

    bf16x8 af[4], bfr[4];
    #pragma unroll
    for (int mt = 0; mt < 4; mt++)
      af[mt] = *(const bf16x8*)&Atile[(wr * 64 + mt * 16 + c15) * 32 + q * 8];
    #pragma unroll
    for (int nt = 0; nt < 4; nt++)
      bfr[nt] = *(const bf16x8*)&Btile[(wc * 64 + nt * 16 + c15) * 32 + q * 8];
    #pragma unroll
    for (int mt = 0; mt < 4; mt++)
      #pragma unroll
      for (int nt = 0; nt < 4; nt++)
        acc[mt][nt] = __builtin_amdgcn_mfma_f32_16x16x32_bf16(af[mt], bfr[nt], acc[mt][nt], 0, 0, 0);
  }

  #pragma unroll
  for (int mt = 0; mt < 4; mt++)
    #pragma unroll
    for (int nt = 0; nt < 4; nt++)
      #pragma unroll
      for (int r = 0; r < 4; r++) {
        const int m = m0 + wr * 64 + mt * 16 + q * 4 + r;
        const int n = n0 + wc * 64 + nt * 16 + c15;
        if constexpr (MODE == 1) {
          ((float*)Cv)[(size_t)m * N + n] = acc[mt][nt][r];
        } else {
          const int which = n >> 10, hh = (n >> 6) & 15, d = n & 63;
          const int bb = m >> 10, i = m & 1023;
          ((unsigned short*)Cv)[(size_t)which * 2097152 +
                                (((size_t)(bb << 4) + hh) << 16) + (i << 6) + d] = f2bf(acc[mt][nt][r]);
        }
      }
}

// ---------------------------------------------------------------------------
// QE[(bh,i)][s] = Qrow . Tpad[s]  (Tpad pre-scaled 1/8) -> fp16, stride 160.
// One MFMA GEMM: M=32768, N=160, K=64. grid 512, block 256 (wave = 16 rows).
// ---------------------------------------------------------------------------
__global__ __launch_bounds__(256) void qe_gemm(const unsigned short* __restrict__ Qh,
                                               const unsigned short* __restrict__ Tpad,
                                               unsigned short* __restrict__ QE)
{
  __shared__ __align__(16) unsigned short T[160][72];  // +8 pad
  const int tid = threadIdx.x;
  const int w = tid >> 6, lane = tid & 63;
  const int c15 = lane & 15, q = lane >> 4;
  const int m0 = blockIdx.x * 64 + w * 16;

  for (int t = tid; t < 1280; t += 256) {
    const int r = t >> 3, c = (t & 7) * 8;
    *(bf16x8*)&T[r][c] = *(const bf16x8*)(Tpad + r * 64 + c);
  }
  __syncthreads();

  bf16x8 a0, a1;
  {
    const unsigned short* ap = Qh + ((size_t)(m0 + c15) << 6) + q * 8;
    a0 = *(const bf16x8*)ap;
    a1 = *(const bf16x8*)(ap + 32);
  }
  unsigned short* out = QE + (size_t)m0 * 160;
  #pragma unroll
  for (int st = 0; st < 10; st++) {
    bf16x8 b0 = *(const bf16x8*)&T[st * 16 + c15][q * 8];
    bf16x8 b1 = *(const bf16x8*)&T[st * 16 + c15][32 + q * 8];
    f32x4 acc; acc[0]=0.f; acc[1]=0.f; acc[2]=0.f; acc[3]=0.f;
    acc = __builtin_amdgcn_mfma_f32_16x16x32_bf16(a0, b0, acc, 0, 0, 0);
    acc = __builtin_amdgcn_mfma_f32_16x16x32_bf16(a1, b1, acc, 0, 0, 0);
    #pragma unroll
    for (int r = 0; r < 4; r++) {
      const _Float16 hv = (_Float16)acc[r];
      unsigned short hb;
      __builtin_memcpy(&hb, &hv, 2);
      out[(size_t)(q * 4 + r) * 160 + st * 16 + c15] = hb;
    }
  }
}

// ---------------------------------------------------------------------------
// Flash attention (ROUND-4 BODY). grid (h=16, y=16, b=2) = 512 blocks;
// block 256 = 4 waves; wave w owns i-rows iw..iw+15 of a 64-row tile.
// it = y, flipped for bb==1 so co-resident blocks pair (long, short).
// LDS 50176 B: Klds/Vtlds (+8 pad), per-wave C2 (bf16, stride 88), QE rows
// fp16 (stride 160). Srel via Er B-frags from global (L2-hot band):
// rbase = 960-i0+j0, wave w tiles pt=3-w..7-w, readback col 15-m+jj.
// Structure bias: packed idx (1 coalesced dword) + 4 LDS fp16 gathers.
// ---------------------------------------------------------------------------
__global__ __launch_bounds__(256) void attn_kernel(
    const unsigned short* __restrict__ QKVh,  // head-major: Q | K | V
    const unsigned short* __restrict__ QE,    // fp16 bits, stride 160
    const unsigned* __restrict__ Pidx,
    const unsigned short* __restrict__ Er,
    unsigned short* __restrict__ Ob)
{
  const int h  = blockIdx.x;
  const int bb = blockIdx.z;
  const int it = bb ? (15 - (int)blockIdx.y) : (int)blockIdx.y;  // co-residency pairing
  const int i0 = it << 6;
  const int tid = threadIdx.x;
  const int w = tid >> 6;
  const int lane = tid & 63;
  const int c15 = lane & 15;
  const int q = lane >> 4;
  const int rowq = q * 4;

  __shared__ __align__(16) unsigned short Klds[64][72];
  __shared__ __align__(16) unsigned short Vtlds[64][72];    // V transposed: [d][j]
  __shared__ __align__(16) unsigned short C2[4][16 * 88];   // per-wave scratch (bf16)
  __shared__ __align__(16) unsigned short qeh[64 * 160];    // QE rows (fp16 bits)
  unsigned short* c2w = &C2[w][0];

  const unsigned short* qhb = QKVh + (((size_t)(bb << 4) + h) << 16);
  const unsigned short* khb = qhb + 2097152;
  const unsigned short* vhb = qhb + 2 * 2097152;

  // ---- stage QE rows (64 x 160 fp16 = 20480 B) ----
  {
    const size_t qeoff = ((((size_t)(bb << 4) + h) * 1024) + i0) * 160;
    const unsigned short* src = QE + qeoff;
    for (int t = tid; t < 10240; t += 256) qeh[t] = src[t];
  }

  // ---- Q fragments, pre-scaled by 1/sqrt(d)=1/8 ----
  bf16x8 qf[2];
  {
    const unsigned short* qp = qhb + ((size_t)(i0 + w * 16 + c15) << 6);
    #pragma unroll
    for (int kk = 0; kk < 2; kk++) {
      B8 t;
      t.v = *(const bf16x8*)(qp + kk * 32 + q * 8);
      #pragma unroll
      for (int e = 0; e < 8; e++) t.u[e] = f2bf(bf2f(t.u[e]) * 0.125f);
      qf[kk] = t.v;
    }
  }

  f32x4 Oa[4];
  float mrow[4], lrow[4];
  #pragma unroll
  for (int dt = 0; dt < 4; dt++) { Oa[dt][0]=0.f; Oa[dt][1]=0.f; Oa[dt][2]=0.f; Oa[dt][3]=0.f; }
  #pragma unroll
  for (int r = 0; r < 4; r++) { mrow[r] = -3e38f; lrow[r] = 0.f; }

  const int iw = i0 + w * 16;
  const size_t idx0 = ((size_t)bb << 20) + ((size_t)(iw + rowq) << 10);

  for (int jt = 0; jt <= it; jt++) {
    const int j0 = jt << 6;
    __syncthreads();  // prev iter's LDS consumers done (also covers qeh stage)

    // ---- stage K (contiguous 8 KB) and V^T ----
    {
      const unsigned short* kt = khb + (j0 << 6);
      *(bf16x8*)&Klds[tid >> 3][(tid & 7) * 8]        = *(const bf16x8*)(kt + tid * 8);
      *(bf16x8*)&Klds[32 + (tid >> 3)][(tid & 7) * 8] = *(const bf16x8*)(kt + 2048 + tid * 8);
      const int vrow = tid >> 2, vcs = (tid & 3) * 16;
      const unsigned short* vt = vhb + (j0 << 6) + (vrow << 6) + vcs;
      B8 v0, v1;
      v0.v = *(const bf16x8*)vt;
      v1.v = *(const bf16x8*)(vt + 8);
      #pragma unroll
      for (int e = 0; e < 8; e++) {
        Vtlds[vcs + e][vrow]     = v0.u[e];
        Vtlds[vcs + 8 + e][vrow] = v1.u[e];
      }
    }
    __syncthreads();

    // ---- QK^T ----
    f32x4 S[4];
    #pragma unroll
    for (int nt = 0; nt < 4; nt++) {
      f32x4 a; a[0]=0.f; a[1]=0.f; a[2]=0.f; a[3]=0.f;
      bf16x8 k0 = *(const bf16x8*)&Klds[nt * 16 + c15][q * 8];
      bf16x8 k1 = *(const bf16x8*)&Klds[nt * 16 + c15][32 + q * 8];
      a = __builtin_amdgcn_mfma_f32_16x16x32_bf16(qf[0], k0, a, 0, 0, 0);
      a = __builtin_amdgcn_mfma_f32_16x16x32_bf16(qf[1], k1, a, 0, 0, 0);
      S[nt] = a;
    }

    // ---- C2 = q . Er-band (Er B-frags from global; 5 of 8 tiles/wave) ----
    {
      const int rbase = 960 - i0 + j0;
      #pragma unroll
      for (int t5 = 0; t5 < 5; t5++) {
        const int pt = 3 - w + t5;
        int row = rbase + pt * 16 + c15;
        row = row > 1023 ? 1023 : row;   // masked-region overrun clamp
        const unsigned short* ep = Er + (row << 6) + q * 8;
        bf16x8 e0 = *(const bf16x8*)ep;
        bf16x8 e1 = *(const bf16x8*)(ep + 32);
        f32x4 a; a[0]=0.f; a[1]=0.f; a[2]=0.f; a[3]=0.f;
        a = __builtin_amdgcn_mfma_f32_16x16x32_bf16(qf[0], e0, a, 0, 0, 0);
        a = __builtin_amdgcn_mfma_f32_16x16x32_bf16(qf[1], e1, a, 0, 0, 0);
        #pragma unroll
        for (int r = 0; r < 4; r++)
          c2w[(rowq + r) * 88 + t5 * 16 + c15] = f2bf(a[r]);
      }
    }

    // ---- scores: + Srel + structure bias (LDS fp16 gathers), causal ----
    #pragma unroll
    for (int nt = 0; nt < 4; nt++) {
      const int j = j0 + nt * 16 + c15;
      unsigned pv[4];
      #pragma unroll
      for (int r = 0; r < 4; r++)
        pv[r] = Pidx[idx0 + ((size_t)r << 10) + j];
      #pragma unroll
      for (int r = 0; r < 4; r++) {
        const int rb = (w * 16 + rowq + r) * 160;
        _Float16 q0, q1, q2, q3;
        __builtin_memcpy(&q0, &qeh[rb + (pv[r] & 31)], 2);
        __builtin_memcpy(&q1, &qeh[rb + ((pv[r] >> 5) & 127)], 2);
        __builtin_memcpy(&q2, &qeh[rb + ((pv[r] >> 12) & 255)], 2);
        __builtin_memcpy(&q3, &qeh[rb + (pv[r] >> 20)], 2);
        const float bias = (float)(q0 + q1) + (float)(q2 + q3);
        const float srel = bf2f(c2w[(rowq + r) * 88 + (15 - (rowq + r) + nt * 16 + c15)]);
        float sc = S[nt][r] + srel + bias;
        if (jt == it && j > iw + rowq + r) sc = -3e38f;  // causal
        S[nt][r] = sc;
      }
    }

    // ---- online softmax ----
    float alpha[4];
    #pragma unroll
    for (int r = 0; r < 4; r++) {
      float v = fmaxf(fmaxf(S[0][r], S[1][r]), fmaxf(S[2][r], S[3][r]));
      v = fmaxf(v, __shfl_xor(v, 1));
      v = fmaxf(v, __shfl_xor(v, 2));
      v = fmaxf(v, __shfl_xor(v, 4));
      v = fmaxf(v, __shfl_xor(v, 8));
      const float mn = fmaxf(mrow[r], v);
      alpha[r] = __expf(mrow[r] - mn);
      mrow[r] = mn;
    }
    #pragma unroll
    for (int nt = 0; nt < 4; nt++)
      #pragma unroll
      for (int r = 0; r < 4; r++)
        S[nt][r] = __expf(S[nt][r] - mrow[r]);
    #pragma unroll
    for (int r = 0; r < 4; r++) {
      float s = S[0][r] + S[1][r] + S[2][r] + S[3][r];
      s += __shfl_xor(s, 1);
      s += __shfl_xor(s, 2);
      s += __shfl_xor(s, 4);
      s += __shfl_xor(s, 8);
      lrow[r] = lrow[r] * alpha[r] + s;
      #pragma unroll
      for (int dt = 0; dt < 4; dt++) Oa[dt][r] *= alpha[r];
    }

    // ---- P round-trip (per-wave LDS, bf16; read back as ds_read_b128) ----
    #pragma unroll
    for (int nt = 0; nt < 4; nt++)
      #pragma unroll
      for (int r = 0; r < 4; r++)
        c2w[(rowq + r) * 88 + nt * 16 + c15] = f2bf(S[nt][r]);

    bf16x8 pf[2];
    #pragma unroll
    for (int kk = 0; kk < 2; kk++)
      pf[kk] = *(const bf16x8*)&c2w[c15 * 88 + kk * 32 + q * 8];

    // ---- O += P @ V ----
    #pragma unroll
    for (int dt = 0; dt < 4; dt++) {
      bf16x8 v0 = *(const bf16x8*)&Vtlds[dt * 16 + c15][q * 8];
      bf16x8 v1 = *(const bf16x8*)&Vtlds[dt * 16 + c15][32 + q * 8];
      Oa[dt] = __builtin_amdgcn_mfma_f32_16x16x32_bf16(pf[0], v0, Oa[dt], 0, 0, 0);
      Oa[dt] = __builtin_amdgcn_mfma_f32_16x16x32_bf16(pf[1], v1, Oa[dt], 0, 0, 0);
    }
  }

  // ---- epilogue: O / l -> Ob (b, i, h*64+d) bf16 ----
  #pragma unroll
  for (int dt = 0; dt < 4; dt++)
    #pragma unroll
    for (int r = 0; r < 4; r++) {
      const int i_ = iw + rowq + r;
      const float o = Oa[dt][r] / lrow[r];
      Ob[(((size_t)bb << 10) + i_) * 1024 + (h << 6) + dt * 16 + c15] = f2bf(o);
    }
}

// ---------------------------------------------------------------------------
extern "C" void kernel_launch(void* const* d_in, const int* in_sizes, int n_in,
                              void* d_out, int out_size, void* d_ws, size_t ws_size,
                              hipStream_t stream)
{
  const float* x    = (const float*)d_in[0];
  const int*   rbar = (const int*)d_in[1];
  const int*   rpos = (const int*)d_in[2];
  const int*   roct = (const int*)d_in[3];
  const int*   rsem = (const int*)d_in[4];
  const float* Wq   = (const float*)d_in[5];
  const float* Wk   = (const float*)d_in[6];
  const float* Wv   = (const float*)d_in[7];
  const float* Wo   = (const float*)d_in[8];
  const float* Er   = (const float*)d_in[9];
  const float* Tb   = (const float*)d_in[10];
  const float* Tp   = (const float*)d_in[11];
  const float* To   = (const float*)d_in[12];
  const float* Ts   = (const float*)d_in[13];
  float* out = (float*)d_out;

  // workspace layout (~47 MB)
  char* ws = (char*)d_ws;
  const size_t MB = 1u << 20;
  unsigned short* x_bf    = (unsigned short*)(ws);             //  4 MB
  unsigned short* Wqkv_bf = (unsigned short*)(ws + 4 * MB);    //  6 MB
  unsigned short* Wo_bf   = (unsigned short*)(ws + 10 * MB);   //  2 MB
  unsigned short* Er_bf   = (unsigned short*)(ws + 12 * MB);   //  128 KB
  unsigned short* Tpad    = (unsigned short*)(ws + 12 * MB + 256 * 1024);  // 20 KB
  unsigned short* QKVh    = (unsigned short*)(ws + 13 * MB);   // 12 MB (head-major Q|K|V)
  unsigned short* Ob      = (unsigned short*)(ws + 25 * MB);   //  4 MB
  unsigned short* QE      = (unsigned short*)(ws + 29 * MB);   // 10 MB (fp16 bits, stride 160)
  unsigned*       Pidx    = (unsigned*)(ws + 39 * MB);         //  8 MB

  cast_all<<<1024, 256, 0, stream>>>(x, Wq, Wk, Wv, Wo, Er, x_bf, Wqkv_bf, Wo_bf, Er_bf);
  build_tpad<<<40, 256, 0, stream>>>(Tb, Tp, To, Ts, Tpad);
  pack_idx<<<1024, 256, 0, stream>>>(rbar, rpos, roct, rsem, Pidx, 524288);

  gemm128<2><<<dim3(24, 16), 256, 0, stream>>>(x_bf, Wqkv_bf, QKVh, 2048, 3072, 1024);
  qe_gemm<<<512, 256, 0, stream>>>(QKVh, Tpad, QE);
  attn_kernel<<<dim3(16, 16, 2), 256, 0, stream>>>(QKVh, QE, Pidx, Er_bf, Ob);
  gemm128<1><<<dim3(8, 16), 256, 0, stream>>>(Ob, Wo_bf, out, 2048, 1024, 1024);
}